// Round 2
// baseline (94.428 us; speedup 1.0000x reference)
//
#include <hip/hip_runtime.h>

// AdaptiveRankingLoss, N=8192, fp32 in / scalar fp32 out.
//
// Symmetry: term(i,j) == term(j,i) and the diagonal is masked (tdiff==0), so
// the sum over ALL ordered pairs divided by the ordered-pair count equals the
// reference's upper-triangular mean exactly.
//
// R1 -> R2: removed LDS staging (j-data is wave-uniform -> scalar s_load into
// SGPRs), removed the divergent `if` (fully predicated ?: arithmetic),
// med3-based clamp folded into an FMA. Target ~13 VALU + 1 rcp per pair.

constexpr int BLOCK = 256;   // one i per thread
constexpr int TJ    = 256;   // j-span per block (uniform inner loop)

__global__ __launch_bounds__(BLOCK) void arl_pair_kernel(
    const float* __restrict__ pred, const float* __restrict__ targ,
    const float* __restrict__ unc, int n,
    double* __restrict__ loss_out, unsigned long long* __restrict__ cnt_out)
{
    const int tid = threadIdx.x;
    const int i   = blockIdx.x * BLOCK + tid;
    const int j0  = blockIdx.y * TJ;

    float acc  = 0.0f;
    float cntf = 0.0f;

    if (i < n) {
        const float pi  = pred[i];
        const float ti  = targ[i];
        const float ui1 = 1.0f + unc[i];
        const int jmax = (n - j0 < TJ) ? (n - j0) : TJ;
        // j0 + jj is wave-uniform -> compiler emits batched s_load into SGPRs;
        // each VALU op below consumes at most one SGPR source (legal).
        #pragma unroll 16
        for (int jj = 0; jj < jmax; ++jj) {
            const float tj = targ[j0 + jj];
            const float pj = pred[j0 + jj];
            const float uj = unc[j0 + jj];
            const float tdiff = ti - tj;
            const float pdiff = pi - pj;
            // margin/0.1 = med3(|tdiff|, 0.1, 1.0)
            const float m3  = __builtin_amdgcn_fmed3f(fabsf(tdiff), 0.1f, 1.0f);
            // sign(tdiff)*pdiff for tdiff!=0 (tdiff==0 handled by mask below)
            const float spd = (tdiff < 0.0f) ? -pdiff : pdiff;
            // h = max(0.1*m3 - spd, 0)  (one fma + one max)
            const float h   = fmaxf(fmaf(m3, 0.1f, -spd), 0.0f);
            const float w   = __builtin_amdgcn_rcpf(ui1 + uj);   // 1/(1+u_i+u_j)
            const bool  nz  = (tdiff != 0.0f);
            const float hm  = nz ? h : 0.0f;
            acc  = fmaf(w, hm, acc);
            cntf += nz ? 1.0f : 0.0f;    // per-thread count <= TJ, exact in fp32
        }
    }

    // wave (64-lane) reduction
    for (int off = 32; off > 0; off >>= 1) {
        acc  += __shfl_down(acc, off);
        cntf += __shfl_down(cntf, off);
    }

    __shared__ float wacc[BLOCK / 64];
    __shared__ float wcnt[BLOCK / 64];
    const int lane = tid & 63;
    const int wid  = tid >> 6;
    if (lane == 0) { wacc[wid] = acc; wcnt[wid] = cntf; }
    __syncthreads();

    if (tid == 0) {
        float a2 = 0.0f, c2 = 0.0f;
        #pragma unroll
        for (int w = 0; w < BLOCK / 64; ++w) { a2 += wacc[w]; c2 += wcnt[w]; }
        atomicAdd(loss_out, (double)a2);
        // per-block count <= 65536, exact in fp32
        atomicAdd(cnt_out, (unsigned long long)(c2 + 0.5f));
    }
}

__global__ void arl_finalize(const double* __restrict__ loss,
                             const unsigned long long* __restrict__ cnt,
                             float* __restrict__ out)
{
    const unsigned long long c = *cnt;
    const double denom = (double)(c ? c : 1ull);
    out[0] = (float)(*loss / denom);
}

extern "C" void kernel_launch(void* const* d_in, const int* in_sizes, int n_in,
                              void* d_out, int out_size, void* d_ws, size_t ws_size,
                              hipStream_t stream) {
    const float* pred = (const float*)d_in[0];
    const float* targ = (const float*)d_in[1];
    const float* unc  = (const float*)d_in[2];
    const int n = in_sizes[0];

    double* loss = (double*)d_ws;
    unsigned long long* cnt = (unsigned long long*)((char*)d_ws + 8);

    hipMemsetAsync(d_ws, 0, 16, stream);  // ws is poisoned 0xAA before every call

    dim3 grid((n + BLOCK - 1) / BLOCK, (n + TJ - 1) / TJ);
    arl_pair_kernel<<<grid, BLOCK, 0, stream>>>(pred, targ, unc, n, loss, cnt);
    arl_finalize<<<1, 1, 0, stream>>>(loss, cnt, (float*)d_out);
}

// Round 3
// 84.971 us; speedup vs baseline: 1.1113x; 1.1113x over previous
//
#include <hip/hip_runtime.h>

// AdaptiveRankingLoss, N=8192, fp32 in / scalar fp32 out.
//
// mean over upper-triangular pairs (i<j, tdiff!=0) of w*hinge.
// R2 -> R3:
//  * no hipMemsetAsync node (39us floor per tiny node!) -- per-block partials
//    into d_ws, reduced by a second kernel; no atomics, no zero-init needed.
//  * triangular tile scheduling: only jt>=it tiles do work (halves pair count);
//    diagonal tiles apply a j>i predicate (block-uniform branch, templated).
//  * slimmer inner loop: xor-sign trick, med3 clamp, rcp; ~13 VALU/pair.
//  * 128x128 tiles, 128-thread blocks -> 2080 working blocks, ~16 waves/CU.

constexpr int TILE = 128;

template<bool DIAG>
__device__ __forceinline__ void tile_loop(
    const float* __restrict__ pred, const float* __restrict__ targ,
    const float* __restrict__ unc, int i, int j0,
    float pi, float ti, float ui1, float& acc, float& cntf)
{
    #pragma unroll 8
    for (int jj = 0; jj < TILE; ++jj) {
        const int jg = j0 + jj;              // wave-uniform -> s_load operands
        const float tj = targ[jg];
        const float pj = pred[jg];
        const float uj = unc[jg];
        const float tdiff = ti - tj;
        const float pdiff = pi - pj;
        // margin/0.1 = med3(|tdiff|, 0.1, 1.0)
        const float m3 = __builtin_amdgcn_fmed3f(fabsf(tdiff), 0.1f, 1.0f);
        // sign(tdiff)*pdiff via sign-bit xor (tdiff==+-0 handled by mask)
        const float spd = __uint_as_float(__float_as_uint(pdiff) ^
                                          (__float_as_uint(tdiff) & 0x80000000u));
        const float h = fmaxf(fmaf(m3, 0.1f, -spd), 0.0f);
        const float w = __builtin_amdgcn_rcpf(ui1 + uj);   // 1/(1+u_i+u_j)
        bool use = (tdiff != 0.0f);
        if (DIAG) use = use && (jg > i);
        acc  = fmaf(use ? w : 0.0f, h, acc);
        cntf += use ? 1.0f : 0.0f;           // per-thread <= 8192, exact fp32
    }
}

__global__ __launch_bounds__(TILE) void arl_pair_kernel(
    const float* __restrict__ pred, const float* __restrict__ targ,
    const float* __restrict__ unc, int n, float2* __restrict__ partials)
{
    const int it = blockIdx.x;
    const int jt = blockIdx.y;
    const int bLin = jt * gridDim.x + it;

    float acc = 0.0f, cntf = 0.0f;

    if (jt >= it) {
        const int i  = it * TILE + threadIdx.x;
        const int j0 = jt * TILE;
        if (i < n) {
            const float pi  = pred[i];
            const float ti  = targ[i];
            const float ui1 = 1.0f + unc[i];
            if (j0 + TILE <= n) {
                if (it == jt) tile_loop<true >(pred, targ, unc, i, j0, pi, ti, ui1, acc, cntf);
                else          tile_loop<false>(pred, targ, unc, i, j0, pi, ti, ui1, acc, cntf);
            } else {
                const int jmax = n - j0;
                for (int jj = 0; jj < jmax; ++jj) {
                    const int jg = j0 + jj;
                    const float tdiff = ti - targ[jg];
                    const float pdiff = pi - pred[jg];
                    const float m3 = __builtin_amdgcn_fmed3f(fabsf(tdiff), 0.1f, 1.0f);
                    const float spd = __uint_as_float(__float_as_uint(pdiff) ^
                                                      (__float_as_uint(tdiff) & 0x80000000u));
                    const float h = fmaxf(fmaf(m3, 0.1f, -spd), 0.0f);
                    const float w = __builtin_amdgcn_rcpf(ui1 + unc[jg]);
                    const bool use = (tdiff != 0.0f) && (jg > i);
                    acc  = fmaf(use ? w : 0.0f, h, acc);
                    cntf += use ? 1.0f : 0.0f;
                }
            }
        }
        // block reduce (2 waves)
        for (int off = 32; off > 0; off >>= 1) {
            acc  += __shfl_down(acc, off);
            cntf += __shfl_down(cntf, off);
        }
        __shared__ float sa[TILE / 64], sc[TILE / 64];
        const int lane = threadIdx.x & 63, wid = threadIdx.x >> 6;
        if (lane == 0) { sa[wid] = acc; sc[wid] = cntf; }
        __syncthreads();
        if (threadIdx.x == 0) {
            float a2 = 0.0f, c2 = 0.0f;
            #pragma unroll
            for (int w = 0; w < TILE / 64; ++w) { a2 += sa[w]; c2 += sc[w]; }
            partials[bLin] = float2{a2, c2};
        }
    } else {
        if (threadIdx.x == 0) partials[bLin] = float2{0.0f, 0.0f};
    }
}

__global__ __launch_bounds__(256) void arl_finalize(
    const float2* __restrict__ partials, int nPartials, float* __restrict__ out)
{
    float a = 0.0f, c = 0.0f;
    for (int k = threadIdx.x; k < nPartials; k += 256) {
        const float2 v = partials[k];
        a += v.x; c += v.y;
    }
    for (int off = 32; off > 0; off >>= 1) {
        a += __shfl_down(a, off);
        c += __shfl_down(c, off);
    }
    __shared__ float sa[4], sc[4];
    const int lane = threadIdx.x & 63, wid = threadIdx.x >> 6;
    if (lane == 0) { sa[wid] = a; sc[wid] = c; }
    __syncthreads();
    if (threadIdx.x == 0) {
        double A = 0.0, C = 0.0;
        #pragma unroll
        for (int w = 0; w < 4; ++w) { A += (double)sa[w]; C += (double)sc[w]; }
        out[0] = (float)(A / (C > 0.0 ? C : 1.0));
    }
}

extern "C" void kernel_launch(void* const* d_in, const int* in_sizes, int n_in,
                              void* d_out, int out_size, void* d_ws, size_t ws_size,
                              hipStream_t stream) {
    const float* pred = (const float*)d_in[0];
    const float* targ = (const float*)d_in[1];
    const float* unc  = (const float*)d_in[2];
    const int n = in_sizes[0];

    const int nt = (n + TILE - 1) / TILE;          // 64 for n=8192
    float2* partials = (float2*)d_ws;              // nt*nt float2 = 32 KB, all written

    dim3 grid(nt, nt);
    arl_pair_kernel<<<grid, TILE, 0, stream>>>(pred, targ, unc, n, partials);
    arl_finalize<<<1, 256, 0, stream>>>(partials, nt * nt, (float*)d_out);
}

// Round 4
// 75.812 us; speedup vs baseline: 1.2456x; 1.1208x over previous
//
#include <hip/hip_runtime.h>

// AdaptiveRankingLoss, N=8192, fp32 in / scalar fp32 out.
// mean over pairs (i<j, t_i!=t_j) of hinge(margin - sign(tdiff)*pdiff)/(1+u_i+u_j).
//
// R3 -> R4:
//  * j-tile staged in LDS as float4{t,p,u,pad}: inner loop = 1 ds_read_b128
//    broadcast (all lanes same addr -> 0 conflicts) + ~14 VALU. Removes the
//    unverified "s_load" dependence suspected of causing R3's ~30us pair time.
//  * compact 1D triangular grid: exactly nt*(nt+1)/2 = 2080 blocks, closed-form
//    (row,col) decode; compact partials (2080 float2) -> cheaper finalize.
//  * note: harness re-poisons the 256 MiB d_ws at ~6.8 TB/s = ~39.4 us inside
//    the timed window -- that is the floor; only pair+finalize time is ours.

constexpr int TILE = 128;

__device__ __forceinline__ void pair_op(float pi, float ti, float ui1,
                                        const float4& v, bool extra_ok,
                                        float& acc, float& cntf)
{
    const float tdiff = ti - v.x;
    const float pdiff = pi - v.y;
    const float m3 = __builtin_amdgcn_fmed3f(fabsf(tdiff), 0.1f, 1.0f);
    const float spd = __uint_as_float(__float_as_uint(pdiff) ^
                                      (__float_as_uint(tdiff) & 0x80000000u));
    const float h = fmaxf(fmaf(m3, 0.1f, -spd), 0.0f);
    const float w = __builtin_amdgcn_rcpf(ui1 + v.z);    // 1/(1+u_i+u_j)
    const bool use = (tdiff != 0.0f) && extra_ok;
    acc  = fmaf(use ? w : 0.0f, h, acc);
    cntf += use ? 1.0f : 0.0f;
}

__global__ __launch_bounds__(TILE) void arl_pair_kernel(
    const float* __restrict__ pred, const float* __restrict__ targ,
    const float* __restrict__ unc, int n, int nt,
    float2* __restrict__ partials)
{
    // decode compact upper-triangular tile index k -> (r, c), c >= r
    const int k = blockIdx.x;
    int r = (int)((float)nt + 0.5f - sqrtf(((float)nt + 0.5f) * ((float)nt + 0.5f)
                                           - 2.0f * (float)k));
    if (r < 0) r = 0;
    auto base = [nt](int rr) { return rr * nt - (rr * (rr - 1)) / 2; };
    while (base(r + 1) <= k) ++r;
    while (base(r) > k) --r;
    const int c = r + (k - base(r));

    const int tid = threadIdx.x;
    const int i   = r * TILE + tid;
    const int j0  = c * TILE;

    __shared__ float4 sj[TILE];
    {
        const int jg = j0 + tid;
        const bool v = jg < n;
        sj[tid] = make_float4(v ? targ[jg] : 0.0f, v ? pred[jg] : 0.0f,
                              v ? unc[jg] : 0.0f, 0.0f);
    }
    __syncthreads();

    float acc = 0.0f, cntf = 0.0f;
    const bool full = (j0 + TILE <= n) && (r * TILE + TILE <= n);

    if (i < n) {
        const float pi  = pred[i];
        const float ti  = targ[i];
        const float ui1 = 1.0f + unc[i];
        if (full) {
            if (r != c) {
                #pragma unroll 8
                for (int jj = 0; jj < TILE; ++jj)
                    pair_op(pi, ti, ui1, sj[jj], true, acc, cntf);
            } else {
                #pragma unroll 8
                for (int jj = 0; jj < TILE; ++jj)
                    pair_op(pi, ti, ui1, sj[jj], (j0 + jj) > i, acc, cntf);
            }
        } else {
            const int jmax = (n - j0 < TILE) ? (n - j0) : TILE;
            for (int jj = 0; jj < jmax; ++jj)
                pair_op(pi, ti, ui1, sj[jj], (j0 + jj) > i, acc, cntf);
        }
    }

    // block reduction (2 waves)
    for (int off = 32; off > 0; off >>= 1) {
        acc  += __shfl_down(acc, off);
        cntf += __shfl_down(cntf, off);
    }
    __shared__ float sa[TILE / 64], sc[TILE / 64];
    const int lane = tid & 63, wid = tid >> 6;
    if (lane == 0) { sa[wid] = acc; sc[wid] = cntf; }
    __syncthreads();
    if (tid == 0) {
        float a2 = 0.0f, c2 = 0.0f;
        #pragma unroll
        for (int w = 0; w < TILE / 64; ++w) { a2 += sa[w]; c2 += sc[w]; }
        partials[k] = float2{a2, c2};
    }
}

__global__ __launch_bounds__(256) void arl_finalize(
    const float2* __restrict__ partials, int nPartials, float* __restrict__ out)
{
    float a = 0.0f, c = 0.0f;
    for (int k = threadIdx.x; k < nPartials; k += 256) {
        const float2 v = partials[k];
        a += v.x; c += v.y;
    }
    for (int off = 32; off > 0; off >>= 1) {
        a += __shfl_down(a, off);
        c += __shfl_down(c, off);
    }
    __shared__ float sa[4], sc[4];
    const int lane = threadIdx.x & 63, wid = threadIdx.x >> 6;
    if (lane == 0) { sa[wid] = a; sc[wid] = c; }
    __syncthreads();
    if (threadIdx.x == 0) {
        double A = 0.0, C = 0.0;
        #pragma unroll
        for (int w = 0; w < 4; ++w) { A += (double)sa[w]; C += (double)sc[w]; }
        out[0] = (float)(A / (C > 0.0 ? C : 1.0));
    }
}

extern "C" void kernel_launch(void* const* d_in, const int* in_sizes, int n_in,
                              void* d_out, int out_size, void* d_ws, size_t ws_size,
                              hipStream_t stream) {
    const float* pred = (const float*)d_in[0];
    const float* targ = (const float*)d_in[1];
    const float* unc  = (const float*)d_in[2];
    const int n = in_sizes[0];

    const int nt = (n + TILE - 1) / TILE;          // 64 for n=8192
    const int nTiles = nt * (nt + 1) / 2;          // 2080
    float2* partials = (float2*)d_ws;              // all nTiles entries written

    arl_pair_kernel<<<nTiles, TILE, 0, stream>>>(pred, targ, unc, n, nt, partials);
    arl_finalize<<<1, 256, 0, stream>>>(partials, nTiles, (float*)d_out);
}